// Round 5
// baseline (73.245 us; speedup 1.0000x reference)
//
#include <hip/hip_runtime.h>

// Problem constants (B=1, C=1, H=W=96)
#define NPTS   9216
#define WIDTH  96
#define CHUNK  1024        // i-chunk (256 threads x IPT=4)
#define NCHUNK 9           // 9216/1024
#define NPAIR  45          // NCHUNK*(NCHUNK+1)/2 unordered chunk pairs
#define JSUB   128         // j sub-tile staged in LDS
#define NJSUB  8           // 1024/128
#define IPT    4

// Prescale features by sqrt(log2(e)) so exp(-0.5 d2) == exp2(hs_i + hs_j + dot)
#define KSCALE 1.2011224087864498f

typedef _Float16 half2v __attribute__((ext_vector_type(2)));
union H2F { half2v h; float f; };

// Compute one point's packed feature record from raw inputs.
// Record: { h2(x,y), h2(r,g), h2(b, s_or_0), hs = -0.5|f|^2 (scaled) }
// |f|^2 uses the fp16-ROUNDED features so the diagonal w_ii == 1 to ~1 ulp.
__device__ __forceinline__ void make_feat(int q, const float* __restrict__ s,
                                          const float* __restrict__ img,
                                          bool carry_s,
                                          half2v& xy, half2v& rg, half2v& bs2,
                                          float& hs, float& sv) {
    int yy = q / WIDTH;
    int xx = q - yy * WIDTH;
    sv = s[q];
    float xs = (float)xx * (KSCALE / 15.0f);
    float ys = (float)yy * (KSCALE / 15.0f);
    float rs = img[q]          * (8.0f * KSCALE);
    float gs = img[NPTS + q]   * (8.0f * KSCALE);
    float bs = img[2*NPTS + q] * (8.0f * KSCALE);
    _Float16 xh = (_Float16)xs, yh = (_Float16)ys;
    _Float16 rh = (_Float16)rs, gh = (_Float16)gs, bh = (_Float16)bs;
    float xr = (float)xh, yr = (float)yh, rr = (float)rh, gr = (float)gh, br = (float)bh;
    hs = -0.5f * (xr*xr + yr*yr + rr*rr + gr*gr + br*br);
    xy  = half2v{xh, yh};
    rg  = half2v{rh, gh};
    bs2 = half2v{bh, carry_s ? (_Float16)sv : (_Float16)0.0f};
}

// Single fused kernel. blockIdx.x in [0,45) -> chunk pair (a<=b);
// blockIdx.y in [0,8) -> 128-point j sub-tile of chunk b. Every block does
// 1024 x 128 pairs (uniform work). Symmetric form:
//   S = sum_{a<=b} wt * sum w_ij * g_ij,  g = s_i + s_j - 2 s_i s_j,
//   wt = 0.5 on diagonal chunk pairs (also yields the exact i==j term, w_ii=1).
// Per thread: A = sum_j w, B = sum_j w*s_j; contribution s_i*A + (1-2 s_i)*B.
// Features are recomputed on the fly (0.16 us total redundancy) - no workspace.
__global__ __launch_bounds__(256)
void crf_fused_kernel(const float* __restrict__ s,
                      const float* __restrict__ img,
                      float* __restrict__ out) {
    __shared__ float4 shF[JSUB];
    __shared__ float wavesum[4];

    const int tid = threadIdx.x;

    // Decode triangular pair index -> (a, b), b >= a.
    int p = blockIdx.x, a = 0;
    while (p >= NCHUNK - a) { p -= NCHUNK - a; ++a; }
    const int b = a + p;
    const int ibase = a * CHUNK;
    const int jbase = b * CHUNK + blockIdx.y * JSUB;

    // Stage j-tile features into LDS (first 128 threads, one point each).
    if (tid < JSUB) {
        half2v xy, rg, bs2; float hs, sv;
        make_feat(jbase + tid, s, img, true, xy, rg, bs2, hs, sv);
        H2F u; u.h = xy;
        H2F v; v.h = rg;
        H2F w; w.h = bs2;
        shF[tid] = float4{u.f, v.f, w.f, hs};
    }

    // My IPT=4 i-points (s-lane zeroed so the third fdot2 adds b_i*b_j + 0*s_j).
    half2v xyi[IPT], rgi[IPT], b0i[IPT];
    float  hsi[IPT], svi[IPT];
    #pragma unroll
    for (int k = 0; k < IPT; ++k)
        make_feat(ibase + k * 256 + tid, s, img, false,
                  xyi[k], rgi[k], b0i[k], hsi[k], svi[k]);

    __syncthreads();

    float A[IPT] = {0.f, 0.f, 0.f, 0.f};
    float B[IPT] = {0.f, 0.f, 0.f, 0.f};

    #pragma unroll 4
    for (int j = 0; j < JSUB; ++j) {
        float4 fj = shF[j];                  // one ds_read_b128, broadcast
        H2F u; u.f = fj.x;
        H2F v; v.f = fj.y;
        H2F w; w.f = fj.z;
        const half2v xyj = u.h, rgj = v.h, bsj = w.h;
        const float sjf = (float)w.h.y;      // j's s from the fp16 lane
        #pragma unroll
        for (int k = 0; k < IPT; ++k) {
            float e = hsi[k] + fj.w;
            e = __builtin_amdgcn_fdot2(xyi[k], xyj, e, false);
            e = __builtin_amdgcn_fdot2(rgi[k], rgj, e, false);
            e = __builtin_amdgcn_fdot2(b0i[k], bsj, e, false);  // s-lane x 0
            float wv = __builtin_amdgcn_exp2f(e);
            A[k] += wv;
            B[k] = fmaf(wv, sjf, B[k]);
        }
    }

    float t = 0.0f;
    #pragma unroll
    for (int k = 0; k < IPT; ++k)
        t += svi[k] * A[k] + fmaf(-2.0f * svi[k], B[k], B[k]);

    const float wt = (a == b) ? 0.5f : 1.0f;
    t *= wt * (1.0f / (float)NPTS);

    #pragma unroll
    for (int off = 32; off > 0; off >>= 1)
        t += __shfl_down(t, off, 64);
    if ((tid & 63) == 0) wavesum[tid >> 6] = t;
    __syncthreads();
    if (tid == 0)
        atomicAdd(out, wavesum[0] + wavesum[1] + wavesum[2] + wavesum[3]);
}

extern "C" void kernel_launch(void* const* d_in, const int* in_sizes, int n_in,
                              void* d_out, int out_size, void* d_ws, size_t ws_size,
                              hipStream_t stream) {
    const float* s   = (const float*)d_in[0];   // [1,1,96,96] probs
    const float* img = (const float*)d_in[1];   // [1,3,96,96] rgb
    float* out = (float*)d_out;

    // Stream-ordered zero of the scalar accumulator (graph-capture legal).
    hipMemsetAsync(out, 0, sizeof(float), stream);

    dim3 grid(NPAIR, NJSUB);
    crf_fused_kernel<<<grid, 256, 0, stream>>>(s, img, out);
}

// Round 6
// 71.313 us; speedup vs baseline: 1.0271x; 1.0271x over previous
//
#include <hip/hip_runtime.h>

// Problem constants (B=1, C=1, H=W=96)
#define NPTS   9216
#define WIDTH  96
#define CHUNK  1024        // i/j chunk (256 threads x IPT=4)
#define NCHUNK 9           // 9216/1024
#define NPAIR  45          // NCHUNK*(NCHUNK+1)/2 unordered chunk pairs
#define JSUB   64          // j sub-tile staged in LDS
#define NJSUB  16          // 1024/64
#define IPT    4

// Prescale features by sqrt(log2(e)) so exp(-0.5 d2) == exp2(hs_i + hs_j + dot)
#define KSCALE 1.2011224087864498f

typedef _Float16 half2v __attribute__((ext_vector_type(2)));
union H2F { half2v h; float f; };

// Kernel 1: packed per-point records + zero the scalar output.
//  arrF[p] = { h2(x,y), h2(r,g), h2(b, s_fp16), hs = -0.5|f|^2*log2e }  (16 B)
//  arrS[p] = s (f32)                                                    (4 B)
// |f|^2 uses the fp16-ROUNDED features (b-lane only; s-lane excluded) so the
// diagonal w_ii == 1 to ~1 ulp.
__global__ __launch_bounds__(256)
void crf_feat_kernel(const float* __restrict__ s,
                     const float* __restrict__ img,
                     float4* __restrict__ arrF,
                     float* __restrict__ arrS,
                     float* __restrict__ out) {
    int p = blockIdx.x * 256 + threadIdx.x;
    if (p == 0) out[0] = 0.0f;            // harness re-poisons d_out every launch
    if (p >= NPTS) return;
    int y = p / WIDTH;
    int x = p - y * WIDTH;
    float sv = s[p];
    float xs = (float)x * (KSCALE / 15.0f);
    float ys = (float)y * (KSCALE / 15.0f);
    float rs = img[p]          * (8.0f * KSCALE);
    float gs = img[NPTS + p]   * (8.0f * KSCALE);
    float bs = img[2*NPTS + p] * (8.0f * KSCALE);
    _Float16 xh = (_Float16)xs, yh = (_Float16)ys;
    _Float16 rh = (_Float16)rs, gh = (_Float16)gs, bh = (_Float16)bs;
    float xr = (float)xh, yr = (float)yh, rr = (float)rh, gr = (float)gh, br = (float)bh;
    float hs = -0.5f * (xr*xr + yr*yr + rr*rr + gr*gr + br*br);

    H2F xy; xy.h = half2v{xh, yh};
    H2F rg; rg.h = half2v{rh, gh};
    H2F b0; b0.h = half2v{bh, (_Float16)sv};   // s_j rides the spare fp16 lane

    float4 r;
    r.x = xy.f; r.y = rg.f; r.z = b0.f; r.w = hs;
    arrF[p] = r;
    arrS[p] = sv;
}

// Kernel 2: balanced triangle. blockIdx.x in [0,45) -> chunk pair (a<=b);
// blockIdx.y in [0,16) -> 64-point j sub-tile of chunk b. Every block does
// 1024 x 64 pairs (uniform work). Symmetric form:
//   S = sum_{a<=b} wt * sum w_ij * g_ij,  g = s_i + s_j - 2 s_i s_j,
//   wt = 0.5 on diagonal chunk pairs (also yields the exact i==j term).
// Per thread: A = sum_j w, B = sum_j w*s_j; contribution s_i*A + (1-2 s_i)*B.
__global__ __launch_bounds__(256)
void crf_pair_kernel(const float4* __restrict__ arrF,
                     const float* __restrict__ arrS,
                     float* __restrict__ out) {
    __shared__ float4 shF[JSUB];
    __shared__ float wavesum[4];

    const int tid = threadIdx.x;

    // Decode triangular pair index -> (a, b), b >= a.
    int p = blockIdx.x, a = 0;
    while (p >= NCHUNK - a) { p -= NCHUNK - a; ++a; }
    const int b = a + p;
    const int ibase = a * CHUNK;
    const int jbase = b * CHUNK + blockIdx.y * JSUB;

    if (tid < JSUB) shF[tid] = arrF[jbase + tid];

    // My IPT=4 i-points; zero the s-lane so fdot2 sees (b_i, 0).
    half2v xyi[IPT], rgi[IPT], b0i[IPT];
    float  hsi[IPT], svi[IPT];
    #pragma unroll
    for (int k = 0; k < IPT; ++k) {
        int i = ibase + k * 256 + tid;
        float4 r = arrF[i];
        H2F u; u.f = r.x; xyi[k] = u.h;
        H2F v; v.f = r.y; rgi[k] = v.h;
        H2F w; w.f = r.z; w.h.y = (_Float16)0.0f; b0i[k] = w.h;
        hsi[k] = r.w;
        svi[k] = arrS[i];
    }

    __syncthreads();

    float A[IPT] = {0.f, 0.f, 0.f, 0.f};
    float B[IPT] = {0.f, 0.f, 0.f, 0.f};

    #pragma unroll 4
    for (int j = 0; j < JSUB; ++j) {
        float4 fj = shF[j];                  // one ds_read_b128, broadcast
        H2F u; u.f = fj.x;
        H2F v; v.f = fj.y;
        H2F w; w.f = fj.z;
        const half2v xyj = u.h, rgj = v.h, bsj = w.h;
        const float sjf = (float)w.h.y;      // j's s from the fp16 lane
        #pragma unroll
        for (int k = 0; k < IPT; ++k) {
            float e = hsi[k] + fj.w;
            e = __builtin_amdgcn_fdot2(xyi[k], xyj, e, false);
            e = __builtin_amdgcn_fdot2(rgi[k], rgj, e, false);
            e = __builtin_amdgcn_fdot2(b0i[k], bsj, e, false);  // s-lane x 0
            float wv = __builtin_amdgcn_exp2f(e);
            A[k] += wv;
            B[k] = fmaf(wv, sjf, B[k]);
        }
    }

    float t = 0.0f;
    #pragma unroll
    for (int k = 0; k < IPT; ++k)
        t += svi[k] * A[k] + fmaf(-2.0f * svi[k], B[k], B[k]);

    const float wt = (a == b) ? 0.5f : 1.0f;
    t *= wt * (1.0f / (float)NPTS);

    #pragma unroll
    for (int off = 32; off > 0; off >>= 1)
        t += __shfl_down(t, off, 64);
    if ((tid & 63) == 0) wavesum[tid >> 6] = t;
    __syncthreads();
    if (tid == 0)
        atomicAdd(out, wavesum[0] + wavesum[1] + wavesum[2] + wavesum[3]);
}

extern "C" void kernel_launch(void* const* d_in, const int* in_sizes, int n_in,
                              void* d_out, int out_size, void* d_ws, size_t ws_size,
                              hipStream_t stream) {
    const float* s   = (const float*)d_in[0];   // [1,1,96,96] probs
    const float* img = (const float*)d_in[1];   // [1,3,96,96] rgb
    float* out = (float*)d_out;

    float4* arrF = (float4*)d_ws;               // 9216 * 16 B
    float*  arrS = (float*)(arrF + NPTS);       // 9216 * 4 B

    crf_feat_kernel<<<NPTS/256, 256, 0, stream>>>(s, img, arrF, arrS, out);
    dim3 grid(NPAIR, NJSUB);
    crf_pair_kernel<<<grid, 256, 0, stream>>>(arrF, arrS, out);
}